// Round 2
// baseline (979.049 us; speedup 1.0000x reference)
//
#include <hip/hip_runtime.h>

// Segment softmax; min-stabilizer + eps cancel mathematically:
// out = exp(d) / segment_sum(exp(d)).  |error| <= 2e-5 << 1.66e-2 threshold.
//
// R4: counting-sort pipeline REMOVED. R1 showed the perm-gather hits a
// random-64B throughput wall (~840 GB/s, insensitive to MLP: 280.2us vs
// 280.5us after 8x MLP restructure). Only 6.4MB (under[]) is truly random;
// everything else now streams in edge order at full BW:
//   kunder : stream data+idx coalesced, 16 exps/edge, global f32 atomics
//            into under[seg][d] (6.4MB, L2/L3-resident, memory-side RMW).
//            unsafeAtomicAdd -> global_atomic_add_f32 (never a CAS loop).
//   krecip : under = 1/under in place (hoists 51.2M divides to 1.6M rcp).
//   kout   : stream data+idx coalesced, gather 16B of 1/under per quad
//            (cache-resident), out = exp * rcp, coalesced 64B-row stores.
// Layout: quad (4 lanes) per edge, lane4 = t&3 owns 16B of the row; UNR=4
// edge-streams per quad, u-streams offset by nq so every wave instruction
// touches 16 consecutive rows = contiguous 1KB.

#define NSEG 100000
#define D    16
#define TPB  256
#define UNR  4

__global__ __launch_bounds__(TPB)
void kunder(const float4* __restrict__ data, const int* __restrict__ idx,
            int n, float* __restrict__ under) {
    int t = threadIdx.x;
    int lane4 = t & 3;
    int q  = blockIdx.x * (TPB / 4) + (t >> 2);
    int nq = gridDim.x * (TPB / 4);           // total quads; nq*UNR >= n
    int sg[UNR]; float4 v[UNR];
#pragma unroll
    for (int u = 0; u < UNR; ++u) {           // all 8 loads independent
        int e  = q + u * nq;
        int ec = (e < n) ? e : 0;
        sg[u] = idx[ec];
        v[u]  = data[(size_t)ec * 4 + lane4];
    }
#pragma unroll
    for (int u = 0; u < UNR; ++u) {
        int e = q + u * nq;
        if (e < n) {
            float* U = under + (size_t)sg[u] * D + lane4 * 4;
            unsafeAtomicAdd(U + 0, __expf(v[u].x));
            unsafeAtomicAdd(U + 1, __expf(v[u].y));
            unsafeAtomicAdd(U + 2, __expf(v[u].z));
            unsafeAtomicAdd(U + 3, __expf(v[u].w));
        }
    }
}

__global__ void krecip(float4* __restrict__ under4, int n4) {
    int i = blockIdx.x * blockDim.x + threadIdx.x;
    if (i >= n4) return;
    float4 a = under4[i];
    a.x = 1.f / a.x; a.y = 1.f / a.y; a.z = 1.f / a.z; a.w = 1.f / a.w;
    under4[i] = a;
}

__global__ __launch_bounds__(TPB)
void kout(const float4* __restrict__ data, const int* __restrict__ idx,
          const float4* __restrict__ urec, int n, float4* __restrict__ out) {
    int t = threadIdx.x;
    int lane4 = t & 3;
    int q  = blockIdx.x * (TPB / 4) + (t >> 2);
    int nq = gridDim.x * (TPB / 4);
    int sg[UNR]; float4 v[UNR];
#pragma unroll
    for (int u = 0; u < UNR; ++u) {           // independent streaming loads
        int e  = q + u * nq;
        int ec = (e < n) ? e : 0;
        sg[u] = idx[ec];
        v[u]  = data[(size_t)ec * 4 + lane4];
    }
    float4 r[UNR];
#pragma unroll
    for (int u = 0; u < UNR; ++u)             // dependent gathers, batched
        r[u] = urec[(size_t)sg[u] * 4 + lane4];
#pragma unroll
    for (int u = 0; u < UNR; ++u) {
        int e = q + u * nq;
        if (e < n) {
            float4 o;
            o.x = __expf(v[u].x) * r[u].x;
            o.y = __expf(v[u].y) * r[u].y;
            o.z = __expf(v[u].z) * r[u].z;
            o.w = __expf(v[u].w) * r[u].w;
            out[(size_t)e * 4 + lane4] = o;   // coalesced 1KB per wave instr
        }
    }
}

extern "C" void kernel_launch(void* const* d_in, const int* in_sizes, int n_in,
                              void* d_out, int out_size, void* d_ws, size_t ws_size,
                              hipStream_t stream) {
    const float4* data = (const float4*)d_in[0];
    const int*    idx  = (const int*)d_in[1];
    int n = in_sizes[0] / D;                  // 3.2M edges

    float* under = (float*)d_ws;              // NSEG*D floats = 6.4MB
    hipMemsetAsync(under, 0, (size_t)NSEG * D * sizeof(float), stream);

    int quads  = (n + UNR - 1) / UNR;         // edges per u-stream
    int blocks = (quads + (TPB / 4) - 1) / (TPB / 4);   // 12500 @ n=3.2M

    kunder<<<blocks, TPB, 0, stream>>>(data, idx, n, under);

    int n4 = NSEG * D / 4;                    // 400K float4
    krecip<<<(n4 + TPB - 1) / TPB, TPB, 0, stream>>>((float4*)under, n4);

    kout<<<blocks, TPB, 0, stream>>>(data, idx, (const float4*)under, n,
                                     (float4*)d_out);
}

// Round 3
// 927.050 us; speedup vs baseline: 1.0561x; 1.0561x over previous
//
#include <hip/hip_runtime.h>
#include <hip/hip_fp16.h>

// Segment softmax: out = exp(d) / segment_sum(exp(d)) (min-stabilizer + eps
// cancel mathematically; fp16 interim adds <=1e-3 rel, threshold 1.66e-2).
//
// R5: all RANDOM READS eliminated. R0/R1 showed random-64B reads wall at
// ~800 GB/s (MLP-insensitive); R2 showed global f32 atomics wall at 80G ops/s
// (WRITE_SIZE = 51.2M x 16B). Writes sustained 1.28 TB/s even as RMW atomics,
// so the permutation is now applied on the WRITE side only:
//   khist    : bucket histogram (bucket = seg>>7, 782 buckets)  [stream]
//   kscan    : exclusive scan (1 block)
//   kscatter2: stream data coalesced, exp, pack fp16, scatter 32B rows to
//              sorted positions (clustered ~5-row runs) + perm  [random WRITE]
//   kbsum2   : stream sorted fp16 rows coalesced, LDS-accumulate per bucket
//              (stride-17 pad), write under = 1/sum (recip fused) [stream]
//   kout2    : stream sorted rows + perm, multiply by LDS reciprocals,
//              scatter out[e] f32 rows (e's clustered in 4096-edge windows
//              per claim run -> DRAM page locality)              [windowed WRITE]
// Fallback to R2 atomic path if ws_size < 122MB.

#define NSEG 100000
#define D    16
#define WB   128      // segments per bucket
#define NB   782      // ceil(NSEG/WB)
#define EPB  4096     // edges per block (hist/scatter)
#define TPB  256
#define TPB2 512
#define PAD  17       // LDS stride per segment (16 + 1 pad)
#define S3   2        // kout2 slices per bucket

static __device__ __forceinline__ unsigned pk(float a, float b) {
    __half2 h = __floats2half2_rn(a, b);
    return __builtin_bit_cast(unsigned, h);
}
static __device__ __forceinline__ void unpk(unsigned u, float& a, float& b) {
    __half2 h = __builtin_bit_cast(__half2, u);
    float2 f = __half22float2(h);
    a = f.x; b = f.y;
}

__global__ void khist(const int* __restrict__ idx, int n,
                      unsigned* __restrict__ counts) {
    __shared__ unsigned h[NB];
    for (int j = threadIdx.x; j < NB; j += TPB) h[j] = 0u;
    __syncthreads();
    int base = blockIdx.x * EPB;
#pragma unroll
    for (int it = 0; it < EPB / TPB; ++it) {
        int i = base + it * TPB + threadIdx.x;
        if (i < n) atomicAdd(&h[idx[i] >> 7], 1u);
    }
    __syncthreads();
    for (int j = threadIdx.x; j < NB; j += TPB) {
        unsigned c = h[j];
        if (c) atomicAdd(&counts[j], c);
    }
}

__global__ void kscan(const unsigned* __restrict__ counts,
                      unsigned* __restrict__ starts,
                      unsigned* __restrict__ offs) {
    __shared__ unsigned s[1024];
    int t = threadIdx.x;
    unsigned v = (t < NB) ? counts[t] : 0u;
    s[t] = v;
    __syncthreads();
    for (int d = 1; d < 1024; d <<= 1) {
        unsigned add = (t >= d) ? s[t - d] : 0u;
        __syncthreads();
        s[t] += add;
        __syncthreads();
    }
    if (t < NB) {
        unsigned ex = s[t] - v;
        starts[t] = ex;
        offs[t]   = ex;
    }
}

__global__ __launch_bounds__(TPB)
void kscatter2(const float4* __restrict__ data, const int* __restrict__ idx,
               int n, unsigned* __restrict__ offs,
               unsigned* __restrict__ perm, uint4* __restrict__ val) {
    __shared__ unsigned h[NB];
    for (int j = threadIdx.x; j < NB; j += TPB) h[j] = 0u;
    __syncthreads();
    int base = blockIdx.x * EPB;
    int sg[EPB / TPB];
#pragma unroll
    for (int it = 0; it < EPB / TPB; ++it) {
        int i = base + it * TPB + threadIdx.x;
        sg[it] = (i < n) ? idx[i] : -1;
        if (sg[it] >= 0) atomicAdd(&h[sg[it] >> 7], 1u);
    }
    __syncthreads();
    for (int j = threadIdx.x; j < NB; j += TPB) {
        unsigned c = h[j];
        if (c) h[j] = atomicAdd(&offs[j], c);  // claim contiguous run
    }
    __syncthreads();
#pragma unroll
    for (int it = 0; it < EPB / TPB; ++it) {
        int i = base + it * TPB + threadIdx.x;
        if (sg[it] >= 0) {
            unsigned pos = atomicAdd(&h[sg[it] >> 7], 1u);
            perm[pos] = ((unsigned)i << 7) | ((unsigned)sg[it] & 127u);
            const float4* q = data + (size_t)i * 4;   // lane-stride 64B: wave
            float4 r0 = q[0], r1 = q[1], r2 = q[2], r3 = q[3];  // covers 4KB
            uint4 w0, w1;
            w0.x = pk(__expf(r0.x), __expf(r0.y));
            w0.y = pk(__expf(r0.z), __expf(r0.w));
            w0.z = pk(__expf(r1.x), __expf(r1.y));
            w0.w = pk(__expf(r1.z), __expf(r1.w));
            w1.x = pk(__expf(r2.x), __expf(r2.y));
            w1.y = pk(__expf(r2.z), __expf(r2.w));
            w1.z = pk(__expf(r3.x), __expf(r3.y));
            w1.w = pk(__expf(r3.z), __expf(r3.w));
            val[(size_t)pos * 2 + 0] = w0;            // 32B row, same 64B line
            val[(size_t)pos * 2 + 1] = w1;
        }
    }
}

__global__ __launch_bounds__(TPB2)
void kbsum2(const uint4* __restrict__ val, const unsigned* __restrict__ perm,
            const unsigned* __restrict__ starts, int n,
            float* __restrict__ under) {
    __shared__ float acc[WB * PAD];
    for (int j = threadIdx.x; j < WB * PAD; j += TPB2) acc[j] = 0.f;
    __syncthreads();
    int bb = blockIdx.x;
    unsigned b0 = starts[bb];
    unsigned b1 = (bb + 1 < NB) ? starts[bb + 1] : (unsigned)n;
    int lane2 = threadIdx.x & 1;          // pair of lanes per 32B row
    for (unsigned p = b0 + (threadIdx.x >> 1); p < b1; p += TPB2 / 2) {
        unsigned u = perm[p];
        int ls = (int)(u & 127u);
        uint4 w = val[(size_t)p * 2 + lane2];
        float f0, f1, f2, f3, f4, f5, f6, f7;
        unpk(w.x, f0, f1); unpk(w.y, f2, f3);
        unpk(w.z, f4, f5); unpk(w.w, f6, f7);
        float* A = &acc[ls * PAD + lane2 * 8];
        atomicAdd(A + 0, f0); atomicAdd(A + 1, f1);
        atomicAdd(A + 2, f2); atomicAdd(A + 3, f3);
        atomicAdd(A + 4, f4); atomicAdd(A + 5, f5);
        atomicAdd(A + 6, f6); atomicAdd(A + 7, f7);
    }
    __syncthreads();
    float* ub = under + (size_t)bb * (WB * D);
    for (int j = threadIdx.x; j < WB * D; j += TPB2)
        ub[j] = 1.f / acc[(j >> 4) * PAD + (j & 15)];   // reciprocal fused
}

__global__ __launch_bounds__(TPB)
void kout2(const uint4* __restrict__ val, const unsigned* __restrict__ perm,
           const unsigned* __restrict__ starts,
           const float* __restrict__ under, int n, float4* __restrict__ out) {
    __shared__ float u_lds[WB * PAD];     // 1/under for this bucket
    int bb = blockIdx.x, sl = blockIdx.y;
    const float* ub = under + (size_t)bb * (WB * D);
    for (int j = threadIdx.x; j < WB * D; j += TPB)
        u_lds[(j >> 4) * PAD + (j & 15)] = ub[j];
    __syncthreads();
    unsigned b0 = starts[bb];
    unsigned b1 = (bb + 1 < NB) ? starts[bb + 1] : (unsigned)n;
    unsigned len = b1 - b0;
    unsigned s0 = b0 + (unsigned)(((unsigned long long)len * sl) / S3);
    unsigned s1 = b0 + (unsigned)(((unsigned long long)len * (sl + 1)) / S3);
    int lane2 = threadIdx.x & 1;
    for (unsigned p = s0 + (threadIdx.x >> 1); p < s1; p += TPB / 2) {
        unsigned u = perm[p];
        unsigned e = u >> 7;
        int ls = (int)(u & 127u);
        uint4 w = val[(size_t)p * 2 + lane2];
        float f0, f1, f2, f3, f4, f5, f6, f7;
        unpk(w.x, f0, f1); unpk(w.y, f2, f3);
        unpk(w.z, f4, f5); unpk(w.w, f6, f7);
        const float* U = &u_lds[ls * PAD + lane2 * 8];
        float4 o0, o1;
        o0.x = f0 * U[0]; o0.y = f1 * U[1]; o0.z = f2 * U[2]; o0.w = f3 * U[3];
        o1.x = f4 * U[4]; o1.y = f5 * U[5]; o1.z = f6 * U[6]; o1.w = f7 * U[7];
        float4* op = out + (size_t)e * 4 + lane2 * 2;   // e's windowed ~4096
        op[0] = o0; op[1] = o1;
    }
}

// ---- fallback (R2 atomic path), used only if ws_size < ~122MB ----
__global__ void kunder_fb(const float4* __restrict__ data,
                          const int* __restrict__ idx, int n,
                          float* __restrict__ under) {
    int q = blockIdx.x * (TPB / 4) + (threadIdx.x >> 2);
    if (q >= n) return;
    int l4 = threadIdx.x & 3;
    float4 v = data[(size_t)q * 4 + l4];
    float* U = under + (size_t)idx[q] * D + l4 * 4;
    unsafeAtomicAdd(U + 0, __expf(v.x));
    unsafeAtomicAdd(U + 1, __expf(v.y));
    unsafeAtomicAdd(U + 2, __expf(v.z));
    unsafeAtomicAdd(U + 3, __expf(v.w));
}
__global__ void krecip_fb(float4* __restrict__ u4, int n4) {
    int i = blockIdx.x * blockDim.x + threadIdx.x;
    if (i >= n4) return;
    float4 a = u4[i];
    a.x = 1.f / a.x; a.y = 1.f / a.y; a.z = 1.f / a.z; a.w = 1.f / a.w;
    u4[i] = a;
}
__global__ void kout_fb(const float4* __restrict__ data,
                        const int* __restrict__ idx,
                        const float4* __restrict__ urec, int n,
                        float4* __restrict__ out) {
    int q = blockIdx.x * (TPB / 4) + (threadIdx.x >> 2);
    if (q >= n) return;
    int l4 = threadIdx.x & 3;
    float4 v = data[(size_t)q * 4 + l4];
    float4 r = urec[(size_t)idx[q] * 4 + l4];
    float4 o;
    o.x = __expf(v.x) * r.x; o.y = __expf(v.y) * r.y;
    o.z = __expf(v.z) * r.z; o.w = __expf(v.w) * r.w;
    out[(size_t)q * 4 + l4] = o;
}

extern "C" void kernel_launch(void* const* d_in, const int* in_sizes, int n_in,
                              void* d_out, int out_size, void* d_ws, size_t ws_size,
                              hipStream_t stream) {
    const float4* data = (const float4*)d_in[0];
    const int*    idx  = (const int*)d_in[1];
    int n = in_sizes[0] / D;                   // 3.2M edges

    char* ws = (char*)d_ws;
    size_t underB = (size_t)NB * WB * D * sizeof(float);   // 6.4MB
    size_t valB   = (size_t)n * 32;                        // 102.4MB
    size_t permB  = (size_t)n * sizeof(unsigned);          // 12.8MB
    size_t need   = underB + valB + permB + 3u * NB * sizeof(unsigned) + 256;

    if (ws_size >= need) {
        float*    under  = (float*)ws;
        uint4*    val    = (uint4*)(ws + underB);
        unsigned* perm   = (unsigned*)(ws + underB + valB);
        unsigned* counts = (unsigned*)(ws + underB + valB + permB);
        unsigned* starts = counts + NB;
        unsigned* offs   = starts + NB;

        hipMemsetAsync(counts, 0, NB * sizeof(unsigned), stream);
        int hblocks = (n + EPB - 1) / EPB;
        khist    <<<hblocks, TPB, 0, stream>>>(idx, n, counts);
        kscan    <<<1, 1024, 0, stream>>>(counts, starts, offs);
        kscatter2<<<hblocks, TPB, 0, stream>>>(data, idx, n, offs, perm, val);
        kbsum2   <<<NB, TPB2, 0, stream>>>(val, perm, starts, n, under);
        kout2    <<<dim3(NB, S3), TPB, 0, stream>>>(val, perm, starts, under,
                                                    n, (float4*)d_out);
    } else {
        float* under = (float*)ws;             // needs only 6.4MB
        hipMemsetAsync(under, 0, (size_t)NSEG * D * sizeof(float), stream);
        int blocks = (n + (TPB / 4) - 1) / (TPB / 4);
        kunder_fb<<<blocks, TPB, 0, stream>>>(data, idx, n, under);
        int n4 = NSEG * D / 4;
        krecip_fb<<<(n4 + TPB - 1) / TPB, TPB, 0, stream>>>((float4*)under, n4);
        kout_fb<<<blocks, TPB, 0, stream>>>(data, idx, (const float4*)under,
                                            n, (float4*)d_out);
    }
}

// Round 4
// 896.520 us; speedup vs baseline: 1.0921x; 1.0341x over previous
//
#include <hip/hip_runtime.h>
#include <hip/hip_fp16.h>

// Segment softmax: out = exp(d) / segment_sum(exp(d)) (min-stabilizer + eps
// cancel mathematically; fp16 interim adds <=1e-3 rel, threshold 1.66e-2).
//
// R6: R3 showed kbsum2/kout2 were LATENCY chains (VGPR=8, VALUBusy 1%,
// FETCH half-absorbed by L3, 190 GB/s) -- not walls. All sorted-side
// consumers now use batched loads (MLP 4-8); perm[] is DELETED (7-bit
// in-bucket segment tag rides the 16 free fp16 sign bits of each 32B val
// row, duplicated per 16B half so no cross-lane exchange); kout no longer
// reads sorted val at all -- it streams data in edge order and gathers
// 16B fp16 reciprocals from the L2-resident 3.2MB urec.
//   khist    : bucket histogram (bucket = seg>>7, 782 buckets)   [stream]
//   kscan    : exclusive scan (1 block)
//   kscatter2: stream data, exp, pack fp16+tag, scatter 32B rows [rand WRITE]
//   kbsum3   : stream val coalesced (8 rows/thread in flight), LDS-accum
//              per bucket, write urec = 1/sum as fp16            [stream]
//   kout3    : stream data+idx, gather 16B urec (L2-res), out    [stream]
// Fallback to R2 atomic path if ws_size < ~106MB.

#define NSEG 100000
#define D    16
#define WB   128      // segments per bucket
#define NB   782      // ceil(NSEG/WB)
#define EPB  4096     // edges per block (hist/scatter)
#define TPB  256
#define PAD  17       // LDS stride per segment (16 + 1 pad)
#define RUNR 8        // kbsum3 rows in flight per thread
#define UNR3 4        // kout3 edge streams per thread

static __device__ __forceinline__ unsigned pk(float a, float b) {
    __half2 h = __floats2half2_rn(a, b);
    return __builtin_bit_cast(unsigned, h);
}
static __device__ __forceinline__ void unpk(unsigned u, float& a, float& b) {
    __half2 h = __builtin_bit_cast(__half2, u);
    float2 f = __half22float2(h);
    a = f.x; b = f.y;
}

__global__ void khist(const int* __restrict__ idx, int n,
                      unsigned* __restrict__ counts) {
    __shared__ unsigned h[NB];
    for (int j = threadIdx.x; j < NB; j += TPB) h[j] = 0u;
    __syncthreads();
    int base = blockIdx.x * EPB;
#pragma unroll
    for (int it = 0; it < EPB / TPB; ++it) {
        int i = base + it * TPB + threadIdx.x;
        if (i < n) atomicAdd(&h[idx[i] >> 7], 1u);
    }
    __syncthreads();
    for (int j = threadIdx.x; j < NB; j += TPB) {
        unsigned c = h[j];
        if (c) atomicAdd(&counts[j], c);
    }
}

__global__ void kscan(const unsigned* __restrict__ counts,
                      unsigned* __restrict__ starts,
                      unsigned* __restrict__ offs) {
    __shared__ unsigned s[1024];
    int t = threadIdx.x;
    unsigned v = (t < NB) ? counts[t] : 0u;
    s[t] = v;
    __syncthreads();
    for (int d = 1; d < 1024; d <<= 1) {
        unsigned add = (t >= d) ? s[t - d] : 0u;
        __syncthreads();
        s[t] += add;
        __syncthreads();
    }
    if (t < NB) {
        unsigned ex = s[t] - v;
        starts[t] = ex;
        offs[t]   = ex;
    }
}

// Pack one 64B f32 row -> 32B (16 fp16) with 7-bit tag duplicated into the
// sign bits of each 16B half: word u (u=0..3) carries tag bit 2u at bit15
// and tag bit 2u+1 at bit31; words 4..7 repeat the same pattern.
static __device__ __forceinline__ void pack_row(const float4& r0, const float4& r1,
                                                const float4& r2, const float4& r3,
                                                unsigned tag, uint4& w0, uint4& w1) {
    unsigned w[8];
    w[0] = pk(__expf(r0.x), __expf(r0.y));
    w[1] = pk(__expf(r0.z), __expf(r0.w));
    w[2] = pk(__expf(r1.x), __expf(r1.y));
    w[3] = pk(__expf(r1.z), __expf(r1.w));
    w[4] = pk(__expf(r2.x), __expf(r2.y));
    w[5] = pk(__expf(r2.z), __expf(r2.w));
    w[6] = pk(__expf(r3.x), __expf(r3.y));
    w[7] = pk(__expf(r3.z), __expf(r3.w));
#pragma unroll
    for (int u = 0; u < 4; ++u) {
        unsigned sb = (((tag >> (2 * u)) & 1u) << 15) |
                      (((tag >> (2 * u + 1)) & 1u) << 31);
        w[u]     |= sb;
        w[u + 4] |= sb;
    }
    w0 = make_uint4(w[0], w[1], w[2], w[3]);
    w1 = make_uint4(w[4], w[5], w[6], w[7]);
}

__global__ __launch_bounds__(TPB)
void kscatter2(const float4* __restrict__ data, const int* __restrict__ idx,
               int n, unsigned* __restrict__ offs, uint4* __restrict__ val) {
    __shared__ unsigned h[NB];
    for (int j = threadIdx.x; j < NB; j += TPB) h[j] = 0u;
    __syncthreads();
    int base = blockIdx.x * EPB;
    int sg[EPB / TPB];
#pragma unroll
    for (int it = 0; it < EPB / TPB; ++it) {
        int i = base + it * TPB + threadIdx.x;
        sg[it] = (i < n) ? idx[i] : -1;
        if (sg[it] >= 0) atomicAdd(&h[sg[it] >> 7], 1u);
    }
    __syncthreads();
    for (int j = threadIdx.x; j < NB; j += TPB) {
        unsigned c = h[j];
        if (c) h[j] = atomicAdd(&offs[j], c);  // claim contiguous run
    }
    __syncthreads();
    // 2 edges per chunk: 8 float4 loads in flight before any use
#pragma unroll
    for (int it = 0; it < EPB / TPB; it += 2) {
        int i0 = base + it * TPB + threadIdx.x;
        int i1 = i0 + TPB;
        bool v0 = sg[it] >= 0, v1 = sg[it + 1] >= 0;
        const float4* q0 = data + (size_t)(v0 ? i0 : base) * 4;
        const float4* q1 = data + (size_t)(v1 ? i1 : base) * 4;
        float4 a0 = q0[0], a1 = q0[1], a2 = q0[2], a3 = q0[3];
        float4 c0 = q1[0], c1 = q1[1], c2 = q1[2], c3 = q1[3];
        if (v0) {
            unsigned pos = atomicAdd(&h[sg[it] >> 7], 1u);
            uint4 w0, w1;
            pack_row(a0, a1, a2, a3, (unsigned)sg[it] & 127u, w0, w1);
            val[(size_t)pos * 2 + 0] = w0;
            val[(size_t)pos * 2 + 1] = w1;
        }
        if (v1) {
            unsigned pos = atomicAdd(&h[sg[it + 1] >> 7], 1u);
            uint4 w0, w1;
            pack_row(c0, c1, c2, c3, (unsigned)sg[it + 1] & 127u, w0, w1);
            val[(size_t)pos * 2 + 0] = w0;
            val[(size_t)pos * 2 + 1] = w1;
        }
    }
}

__global__ __launch_bounds__(512)
void kbsum3(const uint4* __restrict__ val, const unsigned* __restrict__ starts,
            int n, unsigned* __restrict__ urec) {
    __shared__ float acc[WB * PAD];
    for (int j = threadIdx.x; j < WB * PAD; j += 512) acc[j] = 0.f;
    __syncthreads();
    int bb = blockIdx.x;
    unsigned b0 = starts[bb];
    unsigned b1 = (bb + 1 < NB) ? starts[bb + 1] : (unsigned)n;
    int lane2 = threadIdx.x & 1;           // which 16B half of the 32B row
    unsigned tp = threadIdx.x >> 1;        // 256 thread-pairs
    for (unsigned q = b0 + tp; q < b1; q += (unsigned)RUNR * 256u) {
        uint4 W[RUNR]; bool ok[RUNR];
#pragma unroll
        for (int u = 0; u < RUNR; ++u) {   // RUNR coalesced 16B loads in flight
            unsigned p = q + (unsigned)u * 256u;
            ok[u] = p < b1;
            W[u] = val[(size_t)(ok[u] ? p : q) * 2 + lane2];
        }
#pragma unroll
        for (int u = 0; u < RUNR; ++u) {
            if (!ok[u]) continue;
            uint4 w = W[u];
            unsigned tag = ((w.x >> 15) & 1u) | ((w.x >> 30) & 2u)
                         | (((w.y >> 15) & 1u) << 2) | (((w.y >> 30) & 2u) << 2)
                         | (((w.z >> 15) & 1u) << 4) | (((w.z >> 30) & 2u) << 4)
                         | (((w.w >> 15) & 1u) << 6);
            w.x &= 0x7FFF7FFFu; w.y &= 0x7FFF7FFFu;
            w.z &= 0x7FFF7FFFu; w.w &= 0x7FFF7FFFu;
            float f0, f1, f2, f3, f4, f5, f6, f7;
            unpk(w.x, f0, f1); unpk(w.y, f2, f3);
            unpk(w.z, f4, f5); unpk(w.w, f6, f7);
            float* A = &acc[tag * PAD + lane2 * 8];
            atomicAdd(A + 0, f0); atomicAdd(A + 1, f1);
            atomicAdd(A + 2, f2); atomicAdd(A + 3, f3);
            atomicAdd(A + 4, f4); atomicAdd(A + 5, f5);
            atomicAdd(A + 6, f6); atomicAdd(A + 7, f7);
        }
    }
    __syncthreads();
    // urec[seg][k] = fp16x2 of 1/sum; empty segs give inf, never gathered
    for (int j = threadIdx.x; j < WB * 8; j += 512) {
        int ls = j >> 3, k = j & 7;
        float a = acc[ls * PAD + 2 * k], b = acc[ls * PAD + 2 * k + 1];
        urec[((size_t)bb * WB + ls) * 8 + k] = pk(1.f / a, 1.f / b);
    }
}

__global__ __launch_bounds__(TPB)
void kout3(const float4* __restrict__ data, const int* __restrict__ idx,
           const uint4* __restrict__ urec, int n, float4* __restrict__ out) {
    int t = threadIdx.x;
    int lane2 = t & 1;                     // which 8-dim half of the edge
    int pr = blockIdx.x * (TPB / 2) + (t >> 1);
    int np = gridDim.x * (TPB / 2);
    int sg[UNR3]; float4 d0[UNR3], d1[UNR3];
#pragma unroll
    for (int u = 0; u < UNR3; ++u) {       // independent streaming loads
        int e = pr + u * np;
        int ec = (e < n) ? e : 0;
        sg[u] = idx[ec];
        const float4* q = data + (size_t)ec * 4 + lane2 * 2;
        d0[u] = q[0]; d1[u] = q[1];
    }
    uint4 r[UNR3];
#pragma unroll
    for (int u = 0; u < UNR3; ++u)         // batched 16B gathers (L2-res 3.2MB)
        r[u] = urec[(size_t)sg[u] * 2 + lane2];
#pragma unroll
    for (int u = 0; u < UNR3; ++u) {
        int e = pr + u * np;
        if (e >= n) continue;
        float g0, g1, g2, g3, g4, g5, g6, g7;
        unpk(r[u].x, g0, g1); unpk(r[u].y, g2, g3);
        unpk(r[u].z, g4, g5); unpk(r[u].w, g6, g7);
        float4 o0, o1;
        o0.x = __expf(d0[u].x) * g0; o0.y = __expf(d0[u].y) * g1;
        o0.z = __expf(d0[u].z) * g2; o0.w = __expf(d0[u].w) * g3;
        o1.x = __expf(d1[u].x) * g4; o1.y = __expf(d1[u].y) * g5;
        o1.z = __expf(d1[u].z) * g6; o1.w = __expf(d1[u].w) * g7;
        float4* op = out + (size_t)e * 4 + lane2 * 2;
        op[0] = o0; op[1] = o1;            // coalesced
    }
}

// ---- fallback (R2 atomic path), used only if ws_size too small ----
__global__ void kunder_fb(const float4* __restrict__ data,
                          const int* __restrict__ idx, int n,
                          float* __restrict__ under) {
    int q = blockIdx.x * (TPB / 4) + (threadIdx.x >> 2);
    if (q >= n) return;
    int l4 = threadIdx.x & 3;
    float4 v = data[(size_t)q * 4 + l4];
    float* U = under + (size_t)idx[q] * D + l4 * 4;
    unsafeAtomicAdd(U + 0, __expf(v.x));
    unsafeAtomicAdd(U + 1, __expf(v.y));
    unsafeAtomicAdd(U + 2, __expf(v.z));
    unsafeAtomicAdd(U + 3, __expf(v.w));
}
__global__ void krecip_fb(float4* __restrict__ u4, int n4) {
    int i = blockIdx.x * blockDim.x + threadIdx.x;
    if (i >= n4) return;
    float4 a = u4[i];
    a.x = 1.f / a.x; a.y = 1.f / a.y; a.z = 1.f / a.z; a.w = 1.f / a.w;
    u4[i] = a;
}
__global__ void kout_fb(const float4* __restrict__ data,
                        const int* __restrict__ idx,
                        const float4* __restrict__ urec, int n,
                        float4* __restrict__ out) {
    int q = blockIdx.x * (TPB / 4) + (threadIdx.x >> 2);
    if (q >= n) return;
    int l4 = threadIdx.x & 3;
    float4 v = data[(size_t)q * 4 + l4];
    float4 r = urec[(size_t)idx[q] * 4 + l4];
    float4 o;
    o.x = __expf(v.x) * r.x; o.y = __expf(v.y) * r.y;
    o.z = __expf(v.z) * r.z; o.w = __expf(v.w) * r.w;
    out[(size_t)q * 4 + l4] = o;
}

extern "C" void kernel_launch(void* const* d_in, const int* in_sizes, int n_in,
                              void* d_out, int out_size, void* d_ws, size_t ws_size,
                              hipStream_t stream) {
    const float4* data = (const float4*)d_in[0];
    const int*    idx  = (const int*)d_in[1];
    int n = in_sizes[0] / D;                   // 3.2M edges

    char* ws = (char*)d_ws;
    size_t urecB = (size_t)NB * WB * 8 * sizeof(unsigned);  // 3.2MB fp16 recips
    size_t valB  = (size_t)n * 32;                          // 102.4MB fp16 rows
    size_t need  = urecB + valB + 3u * NB * sizeof(unsigned) + 256;

    if (ws_size >= need) {
        unsigned* urec   = (unsigned*)ws;
        uint4*    val    = (uint4*)(ws + urecB);
        unsigned* counts = (unsigned*)(ws + urecB + valB);
        unsigned* starts = counts + NB;
        unsigned* offs   = starts + NB;

        hipMemsetAsync(counts, 0, NB * sizeof(unsigned), stream);
        int hblocks = (n + EPB - 1) / EPB;
        khist    <<<hblocks, TPB, 0, stream>>>(idx, n, counts);
        kscan    <<<1, 1024, 0, stream>>>(counts, starts, offs);
        kscatter2<<<hblocks, TPB, 0, stream>>>(data, idx, n, offs, val);
        kbsum3   <<<NB, 512, 0, stream>>>(val, starts, n, urec);
        int npair  = (n + UNR3 - 1) / UNR3;
        int blocks = (npair + (TPB / 2) - 1) / (TPB / 2);
        kout3    <<<blocks, TPB, 0, stream>>>(data, idx, (const uint4*)urec,
                                              n, (float4*)d_out);
    } else {
        float* under = (float*)ws;             // needs only 6.4MB
        hipMemsetAsync(under, 0, (size_t)NSEG * D * sizeof(float), stream);
        int blocks = (n + (TPB / 4) - 1) / (TPB / 4);
        kunder_fb<<<blocks, TPB, 0, stream>>>(data, idx, n, under);
        int n4 = NSEG * D / 4;
        krecip_fb<<<(n4 + TPB - 1) / TPB, TPB, 0, stream>>>((float4*)under, n4);
        kout_fb<<<blocks, TPB, 0, stream>>>(data, idx, (const float4*)under,
                                            n, (float4*)d_out);
    }
}

// Round 5
// 870.660 us; speedup vs baseline: 1.1245x; 1.0297x over previous
//
#include <hip/hip_runtime.h>
#include <hip/hip_fp16.h>

// Segment softmax: out = exp(d) / segment_sum(exp(d)) (min-stabilizer + eps
// cancel mathematically; fp16 interim adds <=1e-3 rel, threshold 1.66e-2).
//
// R7: R4 exposed the real disease. kbsum3 (and R1/R3 predecessors) reported
// VGPR=24 with an intended 8-deep load batch (needs >=32 VGPR): the compiler
// re-interleaved load/process (legal across LDS<->global address spaces),
// silently reducing MLP to 1 -> ~600cy L3 latency chain -> the 280-338us
// plateau seen in EVERY reduction variant. Fix: asm volatile("":::"memory")
// between load-batch and consume loops pins all batched loads before any
// consumer. Applied to kbsum3 / kout3 / kscatter2. No other changes.
//   khist    : bucket histogram (bucket = seg>>7, 782 buckets)   [stream]
//   kscan    : exclusive scan (1 block)
//   kscatter2: stream data, exp, pack fp16+tag, scatter 32B rows [rand WRITE]
//   kbsum3   : stream val coalesced (8 rows/thread REALLY in flight now),
//              LDS-accum per bucket, urec = 1/sum as fp16        [stream]
//   kout3    : stream data+idx, gather 16B urec (L2-res), out    [stream]
// Fallback to R2 atomic path if ws_size < ~106MB.

#define NSEG 100000
#define D    16
#define WB   128      // segments per bucket
#define NB   782      // ceil(NSEG/WB)
#define EPB  4096     // edges per block (hist/scatter)
#define TPB  256
#define PAD  17       // LDS stride per segment (16 + 1 pad)
#define RUNR 8        // kbsum3 rows in flight per thread
#define UNR3 4        // kout3 edge streams per thread

#define LOAD_FENCE() asm volatile("" ::: "memory")

static __device__ __forceinline__ unsigned pk(float a, float b) {
    __half2 h = __floats2half2_rn(a, b);
    return __builtin_bit_cast(unsigned, h);
}
static __device__ __forceinline__ void unpk(unsigned u, float& a, float& b) {
    __half2 h = __builtin_bit_cast(__half2, u);
    float2 f = __half22float2(h);
    a = f.x; b = f.y;
}

__global__ void khist(const int* __restrict__ idx, int n,
                      unsigned* __restrict__ counts) {
    __shared__ unsigned h[NB];
    for (int j = threadIdx.x; j < NB; j += TPB) h[j] = 0u;
    __syncthreads();
    int base = blockIdx.x * EPB;
#pragma unroll
    for (int it = 0; it < EPB / TPB; ++it) {
        int i = base + it * TPB + threadIdx.x;
        if (i < n) atomicAdd(&h[idx[i] >> 7], 1u);
    }
    __syncthreads();
    for (int j = threadIdx.x; j < NB; j += TPB) {
        unsigned c = h[j];
        if (c) atomicAdd(&counts[j], c);
    }
}

__global__ void kscan(const unsigned* __restrict__ counts,
                      unsigned* __restrict__ starts,
                      unsigned* __restrict__ offs) {
    __shared__ unsigned s[1024];
    int t = threadIdx.x;
    unsigned v = (t < NB) ? counts[t] : 0u;
    s[t] = v;
    __syncthreads();
    for (int d = 1; d < 1024; d <<= 1) {
        unsigned add = (t >= d) ? s[t - d] : 0u;
        __syncthreads();
        s[t] += add;
        __syncthreads();
    }
    if (t < NB) {
        unsigned ex = s[t] - v;
        starts[t] = ex;
        offs[t]   = ex;
    }
}

// Pack one 64B f32 row -> 32B (16 fp16) with 7-bit tag duplicated into the
// sign bits of each 16B half: word u (u=0..3) carries tag bit 2u at bit15
// and tag bit 2u+1 at bit31; words 4..7 repeat the same pattern.
static __device__ __forceinline__ void pack_row(const float4& r0, const float4& r1,
                                                const float4& r2, const float4& r3,
                                                unsigned tag, uint4& w0, uint4& w1) {
    unsigned w[8];
    w[0] = pk(__expf(r0.x), __expf(r0.y));
    w[1] = pk(__expf(r0.z), __expf(r0.w));
    w[2] = pk(__expf(r1.x), __expf(r1.y));
    w[3] = pk(__expf(r1.z), __expf(r1.w));
    w[4] = pk(__expf(r2.x), __expf(r2.y));
    w[5] = pk(__expf(r2.z), __expf(r2.w));
    w[6] = pk(__expf(r3.x), __expf(r3.y));
    w[7] = pk(__expf(r3.z), __expf(r3.w));
#pragma unroll
    for (int u = 0; u < 4; ++u) {
        unsigned sb = (((tag >> (2 * u)) & 1u) << 15) |
                      (((tag >> (2 * u + 1)) & 1u) << 31);
        w[u]     |= sb;
        w[u + 4] |= sb;
    }
    w0 = make_uint4(w[0], w[1], w[2], w[3]);
    w1 = make_uint4(w[4], w[5], w[6], w[7]);
}

__global__ __launch_bounds__(TPB)
void kscatter2(const float4* __restrict__ data, const int* __restrict__ idx,
               int n, unsigned* __restrict__ offs, uint4* __restrict__ val) {
    __shared__ unsigned h[NB];
    for (int j = threadIdx.x; j < NB; j += TPB) h[j] = 0u;
    __syncthreads();
    int base = blockIdx.x * EPB;
    int sg[EPB / TPB];
#pragma unroll
    for (int it = 0; it < EPB / TPB; ++it) {
        int i = base + it * TPB + threadIdx.x;
        sg[it] = (i < n) ? idx[i] : -1;
        if (sg[it] >= 0) atomicAdd(&h[sg[it] >> 7], 1u);
    }
    __syncthreads();
    for (int j = threadIdx.x; j < NB; j += TPB) {
        unsigned c = h[j];
        if (c) h[j] = atomicAdd(&offs[j], c);  // claim contiguous run
    }
    __syncthreads();
    // 2 edges per chunk: 8 float4 loads pinned in flight by LOAD_FENCE
#pragma unroll
    for (int it = 0; it < EPB / TPB; it += 2) {
        int i0 = base + it * TPB + threadIdx.x;
        int i1 = i0 + TPB;
        bool v0 = sg[it] >= 0, v1 = sg[it + 1] >= 0;
        const float4* q0 = data + (size_t)(v0 ? i0 : base) * 4;
        const float4* q1 = data + (size_t)(v1 ? i1 : base) * 4;
        float4 a0 = q0[0], a1 = q0[1], a2 = q0[2], a3 = q0[3];
        float4 c0 = q1[0], c1 = q1[1], c2 = q1[2], c3 = q1[3];
        LOAD_FENCE();                      // all 8 loads issued before any use
        if (v0) {
            unsigned pos = atomicAdd(&h[sg[it] >> 7], 1u);
            uint4 w0, w1;
            pack_row(a0, a1, a2, a3, (unsigned)sg[it] & 127u, w0, w1);
            val[(size_t)pos * 2 + 0] = w0;
            val[(size_t)pos * 2 + 1] = w1;
        }
        if (v1) {
            unsigned pos = atomicAdd(&h[sg[it + 1] >> 7], 1u);
            uint4 w0, w1;
            pack_row(c0, c1, c2, c3, (unsigned)sg[it + 1] & 127u, w0, w1);
            val[(size_t)pos * 2 + 0] = w0;
            val[(size_t)pos * 2 + 1] = w1;
        }
    }
}

__global__ __launch_bounds__(512)
void kbsum3(const uint4* __restrict__ val, const unsigned* __restrict__ starts,
            int n, unsigned* __restrict__ urec) {
    __shared__ float acc[WB * PAD];
    for (int j = threadIdx.x; j < WB * PAD; j += 512) acc[j] = 0.f;
    __syncthreads();
    int bb = blockIdx.x;
    unsigned b0 = starts[bb];
    unsigned b1 = (bb + 1 < NB) ? starts[bb + 1] : (unsigned)n;
    int lane2 = threadIdx.x & 1;           // which 16B half of the 32B row
    unsigned tp = threadIdx.x >> 1;        // 256 thread-pairs
    for (unsigned q = b0 + tp; q < b1; q += (unsigned)RUNR * 256u) {
        uint4 W[RUNR]; bool ok[RUNR];
#pragma unroll
        for (int u = 0; u < RUNR; ++u) {   // RUNR coalesced 16B loads
            unsigned p = q + (unsigned)u * 256u;
            ok[u] = p < b1;
            W[u] = val[(size_t)(ok[u] ? p : q) * 2 + lane2];
        }
        LOAD_FENCE();                      // pin all RUNR loads before consume
#pragma unroll
        for (int u = 0; u < RUNR; ++u) {
            if (!ok[u]) continue;
            uint4 w = W[u];
            unsigned tag = ((w.x >> 15) & 1u) | ((w.x >> 30) & 2u)
                         | (((w.y >> 15) & 1u) << 2) | (((w.y >> 30) & 2u) << 2)
                         | (((w.z >> 15) & 1u) << 4) | (((w.z >> 30) & 2u) << 4)
                         | (((w.w >> 15) & 1u) << 6);
            w.x &= 0x7FFF7FFFu; w.y &= 0x7FFF7FFFu;
            w.z &= 0x7FFF7FFFu; w.w &= 0x7FFF7FFFu;
            float f0, f1, f2, f3, f4, f5, f6, f7;
            unpk(w.x, f0, f1); unpk(w.y, f2, f3);
            unpk(w.z, f4, f5); unpk(w.w, f6, f7);
            float* A = &acc[tag * PAD + lane2 * 8];
            atomicAdd(A + 0, f0); atomicAdd(A + 1, f1);
            atomicAdd(A + 2, f2); atomicAdd(A + 3, f3);
            atomicAdd(A + 4, f4); atomicAdd(A + 5, f5);
            atomicAdd(A + 6, f6); atomicAdd(A + 7, f7);
        }
    }
    __syncthreads();
    // urec[seg][k] = fp16x2 of 1/sum; empty segs give inf, never gathered
    for (int j = threadIdx.x; j < WB * 8; j += 512) {
        int ls = j >> 3, k = j & 7;
        float a = acc[ls * PAD + 2 * k], b = acc[ls * PAD + 2 * k + 1];
        urec[((size_t)bb * WB + ls) * 8 + k] = pk(1.f / a, 1.f / b);
    }
}

__global__ __launch_bounds__(TPB)
void kout3(const float4* __restrict__ data, const int* __restrict__ idx,
           const uint4* __restrict__ urec, int n, float4* __restrict__ out) {
    int t = threadIdx.x;
    int lane2 = t & 1;                     // which 8-dim half of the edge
    int pr = blockIdx.x * (TPB / 2) + (t >> 1);
    int np = gridDim.x * (TPB / 2);
    int sg[UNR3]; float4 d0[UNR3], d1[UNR3];
#pragma unroll
    for (int u = 0; u < UNR3; ++u) {       // independent streaming loads
        int e = pr + u * np;
        int ec = (e < n) ? e : 0;
        sg[u] = idx[ec];
        const float4* q = data + (size_t)ec * 4 + lane2 * 2;
        d0[u] = q[0]; d1[u] = q[1];
    }
    LOAD_FENCE();                          // pin 4 idx + 8 float4 loads
    uint4 r[UNR3];
#pragma unroll
    for (int u = 0; u < UNR3; ++u)         // batched 16B gathers (L2-res 3.2MB)
        r[u] = urec[(size_t)sg[u] * 2 + lane2];
    LOAD_FENCE();                          // pin 4 gathers before compute
#pragma unroll
    for (int u = 0; u < UNR3; ++u) {
        int e = pr + u * np;
        if (e >= n) continue;
        float g0, g1, g2, g3, g4, g5, g6, g7;
        unpk(r[u].x, g0, g1); unpk(r[u].y, g2, g3);
        unpk(r[u].z, g4, g5); unpk(r[u].w, g6, g7);
        float4 o0, o1;
        o0.x = __expf(d0[u].x) * g0; o0.y = __expf(d0[u].y) * g1;
        o0.z = __expf(d0[u].z) * g2; o0.w = __expf(d0[u].w) * g3;
        o1.x = __expf(d1[u].x) * g4; o1.y = __expf(d1[u].y) * g5;
        o1.z = __expf(d1[u].z) * g6; o1.w = __expf(d1[u].w) * g7;
        float4* op = out + (size_t)e * 4 + lane2 * 2;
        op[0] = o0; op[1] = o1;            // coalesced
    }
}

// ---- fallback (R2 atomic path), used only if ws_size too small ----
__global__ void kunder_fb(const float4* __restrict__ data,
                          const int* __restrict__ idx, int n,
                          float* __restrict__ under) {
    int q = blockIdx.x * (TPB / 4) + (threadIdx.x >> 2);
    if (q >= n) return;
    int l4 = threadIdx.x & 3;
    float4 v = data[(size_t)q * 4 + l4];
    float* U = under + (size_t)idx[q] * D + l4 * 4;
    unsafeAtomicAdd(U + 0, __expf(v.x));
    unsafeAtomicAdd(U + 1, __expf(v.y));
    unsafeAtomicAdd(U + 2, __expf(v.z));
    unsafeAtomicAdd(U + 3, __expf(v.w));
}
__global__ void krecip_fb(float4* __restrict__ u4, int n4) {
    int i = blockIdx.x * blockDim.x + threadIdx.x;
    if (i >= n4) return;
    float4 a = u4[i];
    a.x = 1.f / a.x; a.y = 1.f / a.y; a.z = 1.f / a.z; a.w = 1.f / a.w;
    u4[i] = a;
}
__global__ void kout_fb(const float4* __restrict__ data,
                        const int* __restrict__ idx,
                        const float4* __restrict__ urec, int n,
                        float4* __restrict__ out) {
    int q = blockIdx.x * (TPB / 4) + (threadIdx.x >> 2);
    if (q >= n) return;
    int l4 = threadIdx.x & 3;
    float4 v = data[(size_t)q * 4 + l4];
    float4 r = urec[(size_t)idx[q] * 4 + l4];
    float4 o;
    o.x = __expf(v.x) * r.x; o.y = __expf(v.y) * r.y;
    o.z = __expf(v.z) * r.z; o.w = __expf(v.w) * r.w;
    out[(size_t)q * 4 + l4] = o;
}

extern "C" void kernel_launch(void* const* d_in, const int* in_sizes, int n_in,
                              void* d_out, int out_size, void* d_ws, size_t ws_size,
                              hipStream_t stream) {
    const float4* data = (const float4*)d_in[0];
    const int*    idx  = (const int*)d_in[1];
    int n = in_sizes[0] / D;                   // 3.2M edges

    char* ws = (char*)d_ws;
    size_t urecB = (size_t)NB * WB * 8 * sizeof(unsigned);  // 3.2MB fp16 recips
    size_t valB  = (size_t)n * 32;                          // 102.4MB fp16 rows
    size_t need  = urecB + valB + 3u * NB * sizeof(unsigned) + 256;

    if (ws_size >= need) {
        unsigned* urec   = (unsigned*)ws;
        uint4*    val    = (uint4*)(ws + urecB);
        unsigned* counts = (unsigned*)(ws + urecB + valB);
        unsigned* starts = counts + NB;
        unsigned* offs   = starts + NB;

        hipMemsetAsync(counts, 0, NB * sizeof(unsigned), stream);
        int hblocks = (n + EPB - 1) / EPB;
        khist    <<<hblocks, TPB, 0, stream>>>(idx, n, counts);
        kscan    <<<1, 1024, 0, stream>>>(counts, starts, offs);
        kscatter2<<<hblocks, TPB, 0, stream>>>(data, idx, n, offs, val);
        kbsum3   <<<NB, 512, 0, stream>>>(val, starts, n, urec);
        int npair  = (n + UNR3 - 1) / UNR3;
        int blocks = (npair + (TPB / 2) - 1) / (TPB / 2);
        kout3    <<<blocks, TPB, 0, stream>>>(data, idx, (const uint4*)urec,
                                              n, (float4*)d_out);
    } else {
        float* under = (float*)ws;             // needs only 6.4MB
        hipMemsetAsync(under, 0, (size_t)NSEG * D * sizeof(float), stream);
        int blocks = (n + (TPB / 4) - 1) / (TPB / 4);
        kunder_fb<<<blocks, TPB, 0, stream>>>(data, idx, n, under);
        int n4 = NSEG * D / 4;
        krecip_fb<<<(n4 + TPB - 1) / TPB, TPB, 0, stream>>>((float4*)under, n4);
        kout_fb<<<blocks, TPB, 0, stream>>>(data, idx, (const float4*)under,
                                            n, (float4*)d_out);
    }
}

// Round 6
// 612.370 us; speedup vs baseline: 1.5988x; 1.4218x over previous
//
#include <hip/hip_runtime.h>
#include <hip/hip_fp16.h>

// Segment softmax: out = exp(d) / segment_sum(exp(d)) (min-stabilizer + eps
// cancel mathematically; fp16 interim adds <=1e-3 rel, threshold 1.66e-2).
//
// R8: the 280-340us plateau tracks the 51.2M LDS f32 atomicAdds, not memory
// (R0/R3/R4/R5: same time across random-HBM / streamed-L3 reads; ~0.25
// lane-atomics/cy/CU = narrow LDS RMW unit; invisible to VALUBusy and the
// bank-conflict counter). kbsum4 deletes them: stage bucket rows in LDS
// (139KB), counting-sort 128 tags (6.4M u32 LDS atomics total, 8x fewer),
// then REGISTER accumulation over sorted runs + __shfl_xor combine.
//   khist    : bucket histogram (bucket = seg>>7, 782 buckets)   [stream]
//   kscan    : exclusive scan (1 block)
//   kscatter2: stream data, exp, pack fp16+tag, scatter 32B rows [rand WRITE]
//   kbsum4   : LDS-staged counting-sort, register reduce, urec=1/sum fp16
//   kout3    : stream data+idx, gather 16B urec (L2-res), out    [stream]
// Fallback to R2 atomic path if ws_size too small.

#define NSEG 100000
#define D    16
#define WB   128      // segments per bucket
#define NB   782      // ceil(NSEG/WB)
#define EPB  4096     // edges per block (hist/scatter)
#define TPB  256
#define CAP  4352     // rows staged per chunk (mean 4096, +4sigma; chunk loop
                      // handles overflow correctly, just slower)
#define UNR3 4        // kout3 edge streams per thread

#define LOAD_FENCE() asm volatile("" ::: "memory")

static __device__ __forceinline__ unsigned pk(float a, float b) {
    __half2 h = __floats2half2_rn(a, b);
    return __builtin_bit_cast(unsigned, h);
}
static __device__ __forceinline__ void unpk(unsigned u, float& a, float& b) {
    __half2 h = __builtin_bit_cast(__half2, u);
    float2 f = __half22float2(h);
    a = f.x; b = f.y;
}

__global__ void khist(const int* __restrict__ idx, int n,
                      unsigned* __restrict__ counts) {
    __shared__ unsigned h[NB];
    for (int j = threadIdx.x; j < NB; j += TPB) h[j] = 0u;
    __syncthreads();
    int base = blockIdx.x * EPB;
#pragma unroll
    for (int it = 0; it < EPB / TPB; ++it) {
        int i = base + it * TPB + threadIdx.x;
        if (i < n) atomicAdd(&h[idx[i] >> 7], 1u);
    }
    __syncthreads();
    for (int j = threadIdx.x; j < NB; j += TPB) {
        unsigned c = h[j];
        if (c) atomicAdd(&counts[j], c);
    }
}

__global__ void kscan(const unsigned* __restrict__ counts,
                      unsigned* __restrict__ starts,
                      unsigned* __restrict__ offs) {
    __shared__ unsigned s[1024];
    int t = threadIdx.x;
    unsigned v = (t < NB) ? counts[t] : 0u;
    s[t] = v;
    __syncthreads();
    for (int d = 1; d < 1024; d <<= 1) {
        unsigned add = (t >= d) ? s[t - d] : 0u;
        __syncthreads();
        s[t] += add;
        __syncthreads();
    }
    if (t < NB) {
        unsigned ex = s[t] - v;
        starts[t] = ex;
        offs[t]   = ex;
    }
}

// Pack one 64B f32 row -> 32B (16 fp16) with 7-bit tag duplicated into the
// sign bits of each 16B half: word u (u=0..3) carries tag bit 2u at bit15
// and tag bit 2u+1 at bit31; words 4..7 repeat the same pattern.
static __device__ __forceinline__ void pack_row(const float4& r0, const float4& r1,
                                                const float4& r2, const float4& r3,
                                                unsigned tag, uint4& w0, uint4& w1) {
    unsigned w[8];
    w[0] = pk(__expf(r0.x), __expf(r0.y));
    w[1] = pk(__expf(r0.z), __expf(r0.w));
    w[2] = pk(__expf(r1.x), __expf(r1.y));
    w[3] = pk(__expf(r1.z), __expf(r1.w));
    w[4] = pk(__expf(r2.x), __expf(r2.y));
    w[5] = pk(__expf(r2.z), __expf(r2.w));
    w[6] = pk(__expf(r3.x), __expf(r3.y));
    w[7] = pk(__expf(r3.z), __expf(r3.w));
#pragma unroll
    for (int u = 0; u < 4; ++u) {
        unsigned sb = (((tag >> (2 * u)) & 1u) << 15) |
                      (((tag >> (2 * u + 1)) & 1u) << 31);
        w[u]     |= sb;
        w[u + 4] |= sb;
    }
    w0 = make_uint4(w[0], w[1], w[2], w[3]);
    w1 = make_uint4(w[4], w[5], w[6], w[7]);
}

static __device__ __forceinline__ unsigned tag_of(const uint4& w) {
    return ((w.x >> 15) & 1u) | ((w.x >> 30) & 2u)
         | (((w.y >> 15) & 1u) << 2) | (((w.y >> 30) & 2u) << 2)
         | (((w.z >> 15) & 1u) << 4) | (((w.z >> 30) & 2u) << 4)
         | (((w.w >> 15) & 1u) << 6);
}

__global__ __launch_bounds__(TPB)
void kscatter2(const float4* __restrict__ data, const int* __restrict__ idx,
               int n, unsigned* __restrict__ offs, uint4* __restrict__ val) {
    __shared__ unsigned h[NB];
    for (int j = threadIdx.x; j < NB; j += TPB) h[j] = 0u;
    __syncthreads();
    int base = blockIdx.x * EPB;
    int sg[EPB / TPB];
#pragma unroll
    for (int it = 0; it < EPB / TPB; ++it) {
        int i = base + it * TPB + threadIdx.x;
        sg[it] = (i < n) ? idx[i] : -1;
        if (sg[it] >= 0) atomicAdd(&h[sg[it] >> 7], 1u);
    }
    __syncthreads();
    for (int j = threadIdx.x; j < NB; j += TPB) {
        unsigned c = h[j];
        if (c) h[j] = atomicAdd(&offs[j], c);  // claim contiguous run
    }
    __syncthreads();
#pragma unroll
    for (int it = 0; it < EPB / TPB; it += 2) {
        int i0 = base + it * TPB + threadIdx.x;
        int i1 = i0 + TPB;
        bool v0 = sg[it] >= 0, v1 = sg[it + 1] >= 0;
        const float4* q0 = data + (size_t)(v0 ? i0 : base) * 4;
        const float4* q1 = data + (size_t)(v1 ? i1 : base) * 4;
        float4 a0 = q0[0], a1 = q0[1], a2 = q0[2], a3 = q0[3];
        float4 c0 = q1[0], c1 = q1[1], c2 = q1[2], c3 = q1[3];
        LOAD_FENCE();
        if (v0) {
            unsigned pos = atomicAdd(&h[sg[it] >> 7], 1u);
            uint4 w0, w1;
            pack_row(a0, a1, a2, a3, (unsigned)sg[it] & 127u, w0, w1);
            val[(size_t)pos * 2 + 0] = w0;
            val[(size_t)pos * 2 + 1] = w1;
        }
        if (v1) {
            unsigned pos = atomicAdd(&h[sg[it + 1] >> 7], 1u);
            uint4 w0, w1;
            pack_row(c0, c1, c2, c3, (unsigned)sg[it + 1] & 127u, w0, w1);
            val[(size_t)pos * 2 + 0] = w0;
            val[(size_t)pos * 2 + 1] = w1;
        }
    }
}

// One block per bucket. Stage rows in LDS, counting-sort by tag, register
// accumulation over sorted runs. Zero f32 LDS atomics.
__global__ __launch_bounds__(512)
void kbsum4(const uint4* __restrict__ val, const unsigned* __restrict__ starts,
            int n, unsigned* __restrict__ urec) {
    __shared__ uint4 rows[CAP * 2];          // 139,264 B  [slot*2 + half]
    __shared__ unsigned short sidx[CAP];     //   8,704 B  sorted -> slot
    __shared__ unsigned char  tg[CAP];       //   4,352 B  tag per slot
    __shared__ unsigned hist[WB];            //     512 B
    __shared__ unsigned ofs[WB];             //     512 B
    __shared__ unsigned segsc[WB];           //     512 B  inclusive scan
    int t = threadIdx.x, bb = blockIdx.x;
    unsigned b0 = starts[bb];
    unsigned b1 = (bb + 1 < NB) ? starts[bb + 1] : (unsigned)n;
    int seg = t >> 2, sub = t & 3;
    int lane2 = sub & 1;                     // which 16B half (elems 0-7 / 8-15)
    int half  = sub >> 1;                    // which half of the seg's run
    float a0 = 0.f, a1 = 0.f, a2 = 0.f, a3 = 0.f,
          a4 = 0.f, a5 = 0.f, a6 = 0.f, a7 = 0.f;

    for (unsigned cb = b0; cb < b1; cb += CAP) {   // single chunk in practice
        unsigned L = b1 - cb; if (L > CAP) L = CAP;
        if (t < WB) hist[t] = 0u;
        __syncthreads();                     // also: prev chunk's reduce done
        // stage 2L uint4 coalesced, 4-deep batches
        {
            size_t gbase = (size_t)cb * 2;
            unsigned lim = 2u * L, j = (unsigned)t;
            for (; j + 3u * 512u < lim; j += 4u * 512u) {
                uint4 x0 = val[gbase + j];
                uint4 x1 = val[gbase + j + 512u];
                uint4 x2 = val[gbase + j + 1024u];
                uint4 x3 = val[gbase + j + 1536u];
                LOAD_FENCE();
                rows[j] = x0; rows[j + 512u] = x1;
                rows[j + 1024u] = x2; rows[j + 1536u] = x3;
            }
            for (; j < lim; j += 512u) rows[j] = val[gbase + j];
        }
        __syncthreads();
        // histogram + tag cache (u32 LDS atomics only)
        for (unsigned s = t; s < L; s += 512u) {
            unsigned tag = tag_of(rows[s * 2]);
            tg[s] = (unsigned char)tag;
            atomicAdd(&hist[tag], 1u);
        }
        __syncthreads();
        // inclusive scan over 128 bins (Hillis-Steele)
        if (t < WB) segsc[t] = hist[t];
        __syncthreads();
        for (int d = 1; d < WB; d <<= 1) {
            unsigned add = 0u;
            if (t < WB && t >= d) add = segsc[t - d];
            __syncthreads();
            if (t < WB) segsc[t] += add;
            __syncthreads();
        }
        if (t < WB) ofs[t] = segsc[t] - hist[t];   // exclusive
        __syncthreads();
        // scatter slot indices into sorted order
        for (unsigned s = t; s < L; s += 512u) {
            unsigned pos = atomicAdd(&ofs[tg[s]], 1u);
            sidx[pos] = (unsigned short)s;
        }
        __syncthreads();
        // register reduce: 4 threads per segment (2 run-halves x 2 row-halves)
        {
            unsigned cnt = hist[seg];
            unsigned lo  = segsc[seg] - cnt;
            unsigned mylo = lo + (cnt * (unsigned)half) / 2u;
            unsigned myhi = lo + (cnt * (unsigned)(half + 1)) / 2u;
            for (unsigned r = mylo; r < myhi; ++r) {
                unsigned slot = sidx[r];
                uint4 w = rows[slot * 2 + lane2];
                w.x &= 0x7FFF7FFFu; w.y &= 0x7FFF7FFFu;
                w.z &= 0x7FFF7FFFu; w.w &= 0x7FFF7FFFu;
                float f0, f1, f2, f3, f4, f5, f6, f7;
                unpk(w.x, f0, f1); unpk(w.y, f2, f3);
                unpk(w.z, f4, f5); unpk(w.w, f6, f7);
                a0 += f0; a1 += f1; a2 += f2; a3 += f3;
                a4 += f4; a5 += f5; a6 += f6; a7 += f7;
            }
        }
    }
    // combine the two run-halves (threads 4s+{0,1} with 4s+{2,3})
    a0 += __shfl_xor(a0, 2); a1 += __shfl_xor(a1, 2);
    a2 += __shfl_xor(a2, 2); a3 += __shfl_xor(a3, 2);
    a4 += __shfl_xor(a4, 2); a5 += __shfl_xor(a5, 2);
    a6 += __shfl_xor(a6, 2); a7 += __shfl_xor(a7, 2);
    if (half == 0) {
        uint4 o;
        o.x = pk(1.f / a0, 1.f / a1);
        o.y = pk(1.f / a2, 1.f / a3);
        o.z = pk(1.f / a4, 1.f / a5);
        o.w = pk(1.f / a6, 1.f / a7);
        ((uint4*)urec)[((size_t)bb * WB + (unsigned)seg) * 2 + (unsigned)lane2] = o;
    }
}

__global__ __launch_bounds__(TPB)
void kout3(const float4* __restrict__ data, const int* __restrict__ idx,
           const uint4* __restrict__ urec, int n, float4* __restrict__ out) {
    int t = threadIdx.x;
    int lane2 = t & 1;                     // which 8-dim half of the edge
    int pr = blockIdx.x * (TPB / 2) + (t >> 1);
    int np = gridDim.x * (TPB / 2);
    int sg[UNR3]; float4 d0[UNR3], d1[UNR3];
#pragma unroll
    for (int u = 0; u < UNR3; ++u) {
        int e = pr + u * np;
        int ec = (e < n) ? e : 0;
        sg[u] = idx[ec];
        const float4* q = data + (size_t)ec * 4 + lane2 * 2;
        d0[u] = q[0]; d1[u] = q[1];
    }
    LOAD_FENCE();
    uint4 r[UNR3];
#pragma unroll
    for (int u = 0; u < UNR3; ++u)
        r[u] = urec[(size_t)sg[u] * 2 + lane2];
    LOAD_FENCE();
#pragma unroll
    for (int u = 0; u < UNR3; ++u) {
        int e = pr + u * np;
        if (e >= n) continue;
        float g0, g1, g2, g3, g4, g5, g6, g7;
        unpk(r[u].x, g0, g1); unpk(r[u].y, g2, g3);
        unpk(r[u].z, g4, g5); unpk(r[u].w, g6, g7);
        float4 o0, o1;
        o0.x = __expf(d0[u].x) * g0; o0.y = __expf(d0[u].y) * g1;
        o0.z = __expf(d0[u].z) * g2; o0.w = __expf(d0[u].w) * g3;
        o1.x = __expf(d1[u].x) * g4; o1.y = __expf(d1[u].y) * g5;
        o1.z = __expf(d1[u].z) * g6; o1.w = __expf(d1[u].w) * g7;
        float4* op = out + (size_t)e * 4 + lane2 * 2;
        op[0] = o0; op[1] = o1;
    }
}

// ---- fallback (R2 atomic path), used only if ws_size too small ----
__global__ void kunder_fb(const float4* __restrict__ data,
                          const int* __restrict__ idx, int n,
                          float* __restrict__ under) {
    int q = blockIdx.x * (TPB / 4) + (threadIdx.x >> 2);
    if (q >= n) return;
    int l4 = threadIdx.x & 3;
    float4 v = data[(size_t)q * 4 + l4];
    float* U = under + (size_t)idx[q] * D + l4 * 4;
    unsafeAtomicAdd(U + 0, __expf(v.x));
    unsafeAtomicAdd(U + 1, __expf(v.y));
    unsafeAtomicAdd(U + 2, __expf(v.z));
    unsafeAtomicAdd(U + 3, __expf(v.w));
}
__global__ void krecip_fb(float4* __restrict__ u4, int n4) {
    int i = blockIdx.x * blockDim.x + threadIdx.x;
    if (i >= n4) return;
    float4 a = u4[i];
    a.x = 1.f / a.x; a.y = 1.f / a.y; a.z = 1.f / a.z; a.w = 1.f / a.w;
    u4[i] = a;
}
__global__ void kout_fb(const float4* __restrict__ data,
                        const int* __restrict__ idx,
                        const float4* __restrict__ urec, int n,
                        float4* __restrict__ out) {
    int q = blockIdx.x * (TPB / 4) + (threadIdx.x >> 2);
    if (q >= n) return;
    int l4 = threadIdx.x & 3;
    float4 v = data[(size_t)q * 4 + l4];
    float4 r = urec[(size_t)idx[q] * 4 + l4];
    float4 o;
    o.x = __expf(v.x) * r.x; o.y = __expf(v.y) * r.y;
    o.z = __expf(v.z) * r.z; o.w = __expf(v.w) * r.w;
    out[(size_t)q * 4 + l4] = o;
}

extern "C" void kernel_launch(void* const* d_in, const int* in_sizes, int n_in,
                              void* d_out, int out_size, void* d_ws, size_t ws_size,
                              hipStream_t stream) {
    const float4* data = (const float4*)d_in[0];
    const int*    idx  = (const int*)d_in[1];
    int n = in_sizes[0] / D;                   // 3.2M edges

    char* ws = (char*)d_ws;
    size_t urecB = (size_t)NB * WB * 8 * sizeof(unsigned);  // 3.2MB fp16 recips
    size_t valB  = (size_t)n * 32;                          // 102.4MB fp16 rows
    size_t need  = urecB + valB + 3u * NB * sizeof(unsigned) + 256;

    if (ws_size >= need) {
        unsigned* urec   = (unsigned*)ws;
        uint4*    val    = (uint4*)(ws + urecB);
        unsigned* counts = (unsigned*)(ws + urecB + valB);
        unsigned* starts = counts + NB;
        unsigned* offs   = starts + NB;

        hipMemsetAsync(counts, 0, NB * sizeof(unsigned), stream);
        int hblocks = (n + EPB - 1) / EPB;
        khist    <<<hblocks, TPB, 0, stream>>>(idx, n, counts);
        kscan    <<<1, 1024, 0, stream>>>(counts, starts, offs);
        kscatter2<<<hblocks, TPB, 0, stream>>>(data, idx, n, offs, val);
        kbsum4   <<<NB, 512, 0, stream>>>(val, starts, n, urec);
        int npair  = (n + UNR3 - 1) / UNR3;
        int blocks = (npair + (TPB / 2) - 1) / (TPB / 2);
        kout3    <<<blocks, TPB, 0, stream>>>(data, idx, (const uint4*)urec,
                                              n, (float4*)d_out);
    } else {
        float* under = (float*)ws;             // needs only 6.4MB
        hipMemsetAsync(under, 0, (size_t)NSEG * D * sizeof(float), stream);
        int blocks = (n + (TPB / 4) - 1) / (TPB / 4);
        kunder_fb<<<blocks, TPB, 0, stream>>>(data, idx, n, under);
        int n4 = NSEG * D / 4;
        krecip_fb<<<(n4 + TPB - 1) / TPB, TPB, 0, stream>>>((float4*)under, n4);
        kout_fb<<<blocks, TPB, 0, stream>>>(data, idx, (const float4*)under,
                                            n, (float4*)d_out);
    }
}

// Round 8
// 508.295 us; speedup vs baseline: 1.9261x; 1.2048x over previous
//
#include <hip/hip_runtime.h>
#include <hip/hip_fp16.h>

// Segment softmax: out = exp(d) / segment_sum(exp(d)) (min-stabilizer + eps
// cancel mathematically; fp16 only on urec => rel err ~5e-4, thresh 1.66e-2).
//
// R10 = R9 resubmit (container infra failure, no counters). One hardening
// change: KEEP() uses a pure input keep-alive ("v" input operand) instead of
// "+v" RMW on a vector-element lvalue. No logic changes.
//
// R9 structure: two structural deletions on top of R8's atomic-free reducer:
//  (1) val[] (102MB write + 102MB read) deleted -- perm (4B/edge) is enough:
//      kbsum5 sorts perm in LDS per bucket then REGISTER-GATHERS f32 rows
//      straight from data. (R0/R1's "random-read wall" was never real
//      evidence: those kernels were LDS-f32-atomic-bound per R5 analysis.
//      This round measures the true gather rate.)
//  (2) contended global claim atomics (612K on 782 hot addrs) deleted:
//      deterministic 2-level counting-sort layout --
//      khist3: per-(block,bucket) counts, stores only;
//      kscanb: scan each bucket across blocks -> offs2, total;
//      kscan : scan bucket totals -> starts;
//      kscatter3: base = starts[bkt]+offs2[blk][bkt], LDS rank, write perm.
//   kbsum5 : per bucket: LDS counting-sort of perm chunk, 4-row batched
//            register gather (8 float4 in flight), f32 accum, urec=1/sum fp16
//   kout3  : stream data+idx, gather 16B urec (L2-res), out   [unchanged]
// Fallback to atomic path if ws too small or grid too large for kscanb.

#define NSEG 100000
#define D    16
#define WB   128      // segments per bucket
#define NB   782      // ceil(NSEG/WB)
#define EPB  4096     // edges per block (hist/scatter)
#define TPB  256
#define CAP  8192     // perm entries staged per chunk in kbsum5 (32KB LDS)
#define UNR3 4        // kout3 edge streams per thread

#define LOAD_FENCE() asm volatile("" ::: "memory")
#define KEEP(x) asm volatile("" :: "v"(x))

static __device__ __forceinline__ unsigned pk(float a, float b) {
    __half2 h = __floats2half2_rn(a, b);
    return __builtin_bit_cast(unsigned, h);
}
static __device__ __forceinline__ void unpk(unsigned u, float& a, float& b) {
    __half2 h = __builtin_bit_cast(__half2, u);
    float2 f = __half22float2(h);
    a = f.x; b = f.y;
}

// per-(block,bucket) histogram; no global atomics anywhere
__global__ __launch_bounds__(TPB)
void khist3(const int* __restrict__ idx, int n, unsigned* __restrict__ counts2) {
    __shared__ unsigned h[NB];
    for (int j = threadIdx.x; j < NB; j += TPB) h[j] = 0u;
    __syncthreads();
    int base = blockIdx.x * EPB;
#pragma unroll
    for (int it = 0; it < EPB / TPB; ++it) {
        int i = base + it * TPB + threadIdx.x;
        if (i < n) atomicAdd(&h[idx[i] >> 7], 1u);
    }
    __syncthreads();
    unsigned* row = counts2 + (size_t)blockIdx.x * NB;   // coalesced stores
    for (int j = threadIdx.x; j < NB; j += TPB) row[j] = h[j];
}

// one block per bucket: scan counts across scatter-blocks -> offs2, total
__global__ __launch_bounds__(1024)
void kscanb(const unsigned* __restrict__ counts2, int nblk,
            unsigned* __restrict__ offs2, unsigned* __restrict__ total) {
    __shared__ unsigned s[1024];
    int j = blockIdx.x, t = threadIdx.x;
    unsigned v = (t < nblk) ? counts2[(size_t)t * NB + j] : 0u;
    s[t] = v;
    __syncthreads();
    for (int d = 1; d < 1024; d <<= 1) {
        unsigned add = (t >= d) ? s[t - d] : 0u;
        __syncthreads();
        s[t] += add;
        __syncthreads();
    }
    if (t < nblk) offs2[(size_t)t * NB + j] = s[t] - v;
    if (t == nblk - 1) total[j] = s[t];
}

__global__ __launch_bounds__(1024)
void kscan(const unsigned* __restrict__ total, unsigned* __restrict__ starts) {
    __shared__ unsigned s[1024];
    int t = threadIdx.x;
    unsigned v = (t < NB) ? total[t] : 0u;
    s[t] = v;
    __syncthreads();
    for (int d = 1; d < 1024; d <<= 1) {
        unsigned add = (t >= d) ? s[t - d] : 0u;
        __syncthreads();
        s[t] += add;
        __syncthreads();
    }
    if (t < NB) starts[t] = s[t] - v;
}

// deterministic scatter: no global atomics, writes 4B/edge
__global__ __launch_bounds__(TPB)
void kscatter3(const int* __restrict__ idx, int n,
               const unsigned* __restrict__ starts,
               const unsigned* __restrict__ offs2,
               unsigned* __restrict__ perm) {
    __shared__ unsigned h[NB];                 // absolute running positions
    const unsigned* row = offs2 + (size_t)blockIdx.x * NB;  // coalesced
    for (int j = threadIdx.x; j < NB; j += TPB)
        h[j] = starts[j] + row[j];
    __syncthreads();
    int base = blockIdx.x * EPB;
#pragma unroll
    for (int it = 0; it < EPB / TPB; ++it) {
        int i = base + it * TPB + threadIdx.x;
        if (i < n) {
            int seg = idx[i];
            unsigned pos = atomicAdd(&h[seg >> 7], 1u);
            perm[pos] = ((unsigned)i << 7) | ((unsigned)seg & 127u);
        }
    }
}

// one block per bucket: LDS counting-sort of perm, register gather+reduce
__global__ __launch_bounds__(512)
void kbsum5(const float4* __restrict__ data, const unsigned* __restrict__ perm,
            const unsigned* __restrict__ starts, int n,
            unsigned* __restrict__ urec) {
    __shared__ unsigned sper[CAP];             // 32KB: tag-sorted perm entries
    __shared__ unsigned hist[WB], segsc[WB], ofs[WB];
    int t = threadIdx.x, bb = blockIdx.x;
    unsigned b0 = starts[bb];
    unsigned b1 = (bb + 1 < NB) ? starts[bb + 1] : (unsigned)n;
    int seg = t >> 2, sub = t & 3;
    int lane2 = sub & 1;                       // which 8-elem (32B) row half
    int half  = sub >> 1;                      // which half of the seg's run
    float a0 = 0.f, a1 = 0.f, a2 = 0.f, a3 = 0.f,
          a4 = 0.f, a5 = 0.f, a6 = 0.f, a7 = 0.f;

    for (unsigned cb = b0; cb < b1; cb += CAP) {   // single chunk in practice
        unsigned L = b1 - cb; if (L > CAP) L = CAP;
        if (t < WB) hist[t] = 0u;
        __syncthreads();
        for (unsigned s = t; s < L; s += 512u)     // coalesced perm read #1
            atomicAdd(&hist[perm[cb + s] & 127u], 1u);
        __syncthreads();
        if (t < WB) segsc[t] = hist[t];
        __syncthreads();
        for (int d = 1; d < WB; d <<= 1) {         // inclusive scan, 128 bins
            unsigned add = (t < WB && t >= d) ? segsc[t - d] : 0u;
            __syncthreads();
            if (t < WB) segsc[t] += add;
            __syncthreads();
        }
        if (t < WB) ofs[t] = segsc[t] - hist[t];
        __syncthreads();
        for (unsigned s = t; s < L; s += 512u) {   // perm read #2 (L2-hot)
            unsigned e = perm[cb + s];
            unsigned pos = atomicAdd(&ofs[e & 127u], 1u);
            sper[pos] = e;
        }
        __syncthreads();
        // register reduce: 4 threads/seg (2 run-halves x 2 row-halves),
        // 4-row batches -> 8 independent float4 gathers in flight
        {
            unsigned cnt = hist[seg];
            unsigned lo  = segsc[seg] - cnt;
            unsigned mylo = lo + (cnt * (unsigned)half) / 2u;
            unsigned myhi = lo + (cnt * (unsigned)(half + 1)) / 2u;
            unsigned r = mylo;
            for (; r + 4u <= myhi; r += 4u) {
                unsigned e0 = sper[r] >> 7,      e1 = sper[r + 1u] >> 7;
                unsigned e2 = sper[r + 2u] >> 7, e3 = sper[r + 3u] >> 7;
                const float4* q0 = data + (size_t)e0 * 4 + lane2 * 2;
                const float4* q1 = data + (size_t)e1 * 4 + lane2 * 2;
                const float4* q2 = data + (size_t)e2 * 4 + lane2 * 2;
                const float4* q3 = data + (size_t)e3 * 4 + lane2 * 2;
                float4 x0 = q0[0], y0 = q0[1], x1 = q1[0], y1 = q1[1];
                float4 x2 = q2[0], y2 = q2[1], x3 = q3[0], y3 = q3[1];
                KEEP(x0.x); KEEP(y0.x); KEEP(x1.x); KEEP(y1.x);
                KEEP(x2.x); KEEP(y2.x); KEEP(x3.x); KEEP(y3.x);
                a0 += __expf(x0.x) + __expf(x1.x) + __expf(x2.x) + __expf(x3.x);
                a1 += __expf(x0.y) + __expf(x1.y) + __expf(x2.y) + __expf(x3.y);
                a2 += __expf(x0.z) + __expf(x1.z) + __expf(x2.z) + __expf(x3.z);
                a3 += __expf(x0.w) + __expf(x1.w) + __expf(x2.w) + __expf(x3.w);
                a4 += __expf(y0.x) + __expf(y1.x) + __expf(y2.x) + __expf(y3.x);
                a5 += __expf(y0.y) + __expf(y1.y) + __expf(y2.y) + __expf(y3.y);
                a6 += __expf(y0.z) + __expf(y1.z) + __expf(y2.z) + __expf(y3.z);
                a7 += __expf(y0.w) + __expf(y1.w) + __expf(y2.w) + __expf(y3.w);
            }
            for (; r < myhi; ++r) {
                unsigned e = sper[r] >> 7;
                const float4* q = data + (size_t)e * 4 + lane2 * 2;
                float4 x = q[0], y = q[1];
                a0 += __expf(x.x); a1 += __expf(x.y);
                a2 += __expf(x.z); a3 += __expf(x.w);
                a4 += __expf(y.x); a5 += __expf(y.y);
                a6 += __expf(y.z); a7 += __expf(y.w);
            }
        }
        __syncthreads();                       // reduce done before next chunk
    }
    // combine run-halves: threads 4s+{0,1} with 4s+{2,3}
    a0 += __shfl_xor(a0, 2); a1 += __shfl_xor(a1, 2);
    a2 += __shfl_xor(a2, 2); a3 += __shfl_xor(a3, 2);
    a4 += __shfl_xor(a4, 2); a5 += __shfl_xor(a5, 2);
    a6 += __shfl_xor(a6, 2); a7 += __shfl_xor(a7, 2);
    if (half == 0) {
        uint4 o;
        o.x = pk(1.f / a0, 1.f / a1);
        o.y = pk(1.f / a2, 1.f / a3);
        o.z = pk(1.f / a4, 1.f / a5);
        o.w = pk(1.f / a6, 1.f / a7);
        ((uint4*)urec)[((size_t)bb * WB + (unsigned)seg) * 2 + (unsigned)lane2] = o;
    }
}

__global__ __launch_bounds__(TPB)
void kout3(const float4* __restrict__ data, const int* __restrict__ idx,
           const uint4* __restrict__ urec, int n, float4* __restrict__ out) {
    int t = threadIdx.x;
    int lane2 = t & 1;                     // which 8-dim half of the edge
    int pr = blockIdx.x * (TPB / 2) + (t >> 1);
    int np = gridDim.x * (TPB / 2);
    int sg[UNR3]; float4 d0[UNR3], d1[UNR3];
#pragma unroll
    for (int u = 0; u < UNR3; ++u) {
        int e = pr + u * np;
        int ec = (e < n) ? e : 0;
        sg[u] = idx[ec];
        const float4* q = data + (size_t)ec * 4 + lane2 * 2;
        d0[u] = q[0]; d1[u] = q[1];
    }
    LOAD_FENCE();
    uint4 r[UNR3];
#pragma unroll
    for (int u = 0; u < UNR3; ++u)
        r[u] = urec[(size_t)sg[u] * 2 + lane2];
    LOAD_FENCE();
#pragma unroll
    for (int u = 0; u < UNR3; ++u) {
        int e = pr + u * np;
        if (e >= n) continue;
        float g0, g1, g2, g3, g4, g5, g6, g7;
        unpk(r[u].x, g0, g1); unpk(r[u].y, g2, g3);
        unpk(r[u].z, g4, g5); unpk(r[u].w, g6, g7);
        float4 o0, o1;
        o0.x = __expf(d0[u].x) * g0; o0.y = __expf(d0[u].y) * g1;
        o0.z = __expf(d0[u].z) * g2; o0.w = __expf(d0[u].w) * g3;
        o1.x = __expf(d1[u].x) * g4; o1.y = __expf(d1[u].y) * g5;
        o1.z = __expf(d1[u].z) * g6; o1.w = __expf(d1[u].w) * g7;
        float4* op = out + (size_t)e * 4 + lane2 * 2;
        op[0] = o0; op[1] = o1;
    }
}

// ---- fallback (atomic path), used only if ws too small / grid too big ----
__global__ void kunder_fb(const float4* __restrict__ data,
                          const int* __restrict__ idx, int n,
                          float* __restrict__ under) {
    int q = blockIdx.x * (TPB / 4) + (threadIdx.x >> 2);
    if (q >= n) return;
    int l4 = threadIdx.x & 3;
    float4 v = data[(size_t)q * 4 + l4];
    float* U = under + (size_t)idx[q] * D + l4 * 4;
    unsafeAtomicAdd(U + 0, __expf(v.x));
    unsafeAtomicAdd(U + 1, __expf(v.y));
    unsafeAtomicAdd(U + 2, __expf(v.z));
    unsafeAtomicAdd(U + 3, __expf(v.w));
}
__global__ void krecip_fb(float4* __restrict__ u4, int n4) {
    int i = blockIdx.x * blockDim.x + threadIdx.x;
    if (i >= n4) return;
    float4 a = u4[i];
    a.x = 1.f / a.x; a.y = 1.f / a.y; a.z = 1.f / a.z; a.w = 1.f / a.w;
    u4[i] = a;
}
__global__ void kout_fb(const float4* __restrict__ data,
                        const int* __restrict__ idx,
                        const float4* __restrict__ urec, int n,
                        float4* __restrict__ out) {
    int q = blockIdx.x * (TPB / 4) + (threadIdx.x >> 2);
    if (q >= n) return;
    int l4 = threadIdx.x & 3;
    float4 v = data[(size_t)q * 4 + l4];
    float4 r = urec[(size_t)idx[q] * 4 + l4];
    float4 o;
    o.x = __expf(v.x) * r.x; o.y = __expf(v.y) * r.y;
    o.z = __expf(v.z) * r.z; o.w = __expf(v.w) * r.w;
    out[(size_t)q * 4 + l4] = o;
}

extern "C" void kernel_launch(void* const* d_in, const int* in_sizes, int n_in,
                              void* d_out, int out_size, void* d_ws, size_t ws_size,
                              hipStream_t stream) {
    const float4* data = (const float4*)d_in[0];
    const int*    idx  = (const int*)d_in[1];
    int n = in_sizes[0] / D;                   // 3.2M edges
    int hblocks = (n + EPB - 1) / EPB;         // 782

    char* ws = (char*)d_ws;
    size_t urecB = (size_t)NB * WB * 8 * sizeof(unsigned);    // 3.2MB
    size_t permB = (size_t)n * sizeof(unsigned);              // 12.8MB
    size_t c2B   = (size_t)hblocks * NB * sizeof(unsigned);   // 2.4MB
    size_t need  = urecB + permB + 2 * c2B + 2 * NB * sizeof(unsigned) + 256;

    if (ws_size >= need && hblocks <= 1024) {
        unsigned* urec   = (unsigned*)ws;
        unsigned* perm   = (unsigned*)(ws + urecB);
        unsigned* counts2= (unsigned*)(ws + urecB + permB);
        unsigned* offs2  = (unsigned*)(ws + urecB + permB + c2B);
        unsigned* total  = (unsigned*)(ws + urecB + permB + 2 * c2B);
        unsigned* starts = total + NB;

        khist3   <<<hblocks, TPB, 0, stream>>>(idx, n, counts2);
        kscanb   <<<NB, 1024, 0, stream>>>(counts2, hblocks, offs2, total);
        kscan    <<<1, 1024, 0, stream>>>(total, starts);
        kscatter3<<<hblocks, TPB, 0, stream>>>(idx, n, starts, offs2, perm);
        kbsum5   <<<NB, 512, 0, stream>>>(data, perm, starts, n, urec);
        int npair  = (n + UNR3 - 1) / UNR3;
        int blocks = (npair + (TPB / 2) - 1) / (TPB / 2);
        kout3    <<<blocks, TPB, 0, stream>>>(data, idx, (const uint4*)urec,
                                              n, (float4*)d_out);
    } else {
        float* under = (float*)ws;             // needs only 6.4MB
        hipMemsetAsync(under, 0, (size_t)NSEG * D * sizeof(float), stream);
        int blocks = (n + (TPB / 4) - 1) / (TPB / 4);
        kunder_fb<<<blocks, TPB, 0, stream>>>(data, idx, n, under);
        int n4 = NSEG * D / 4;
        krecip_fb<<<(n4 + TPB - 1) / TPB, TPB, 0, stream>>>((float4*)under, n4);
        kout_fb<<<blocks, TPB, 0, stream>>>(data, idx, (const float4*)under,
                                            n, (float4*)d_out);
    }
}